// Round 6
// baseline (595.188 us; speedup 1.0000x reference)
//
#include <hip/hip_runtime.h>
#include <math.h>

#define FIN  1433
#define HID  16
#define NCLS 7
#define BM   128
#define BK   32
#define KS   4          // split-K slices
#define KT_TOTAL 45     // ceil(1433/32)

// ---------------- K1: split-K tiled dual GEMM ----------------
// C[n x 32] = x[n x 1433] @ [w_rel1 | w_root1]; grid (ceil(n/128), KS).
// Slice s accumulates its k-tile range into pbase/abase + s*seg.
// LDS x-tile XOR-swizzled (write (c,r) -> xs[c*128+(r^c)]); reads are
// float4 with static component unpermute. Register prefetch overlaps
// next tile's global loads with current tile's compute.
__global__ __launch_bounds__(256) void k1_gemm(
    const float* __restrict__ x,
    const float* __restrict__ w_root, const float* __restrict__ w_rel,
    const float* __restrict__ b_rel,
    float* __restrict__ pbase, float* __restrict__ abase,
    size_t seg_elems, int n) {
  __shared__ float xs[BK * BM];
  __shared__ float ws[BK * 32];

  const int tid   = threadIdx.x;
  const int row0  = blockIdx.x * BM;
  const int slice = blockIdx.y;
  const int cg    = tid & 7;
  const int rg    = tid >> 3;
  const int c0    = cg * 4;
  const int r0    = rg * 4;

  const int kt_beg = (KT_TOTAL * slice) / KS;
  const int kt_end = (KT_TOTAL * (slice + 1)) / KS;

  float acc[4][4];
#pragma unroll
  for (int i = 0; i < 4; ++i)
#pragma unroll
    for (int j = 0; j < 4; ++j) acc[i][j] = 0.f;

  float xreg[16], wreg[4];
  auto prefetch = [&](int kt) {
    const int k0 = kt * BK;
#pragma unroll
    for (int i = 0; i < 16; ++i) {
      int idx = i * 256 + tid;
      int r = idx >> 5, c = idx & 31;
      int gr = row0 + r, gk = k0 + c;
      xreg[i] = (gr < n && gk < FIN) ? x[(size_t)gr * FIN + gk] : 0.f;
    }
#pragma unroll
    for (int i = 0; i < 4; ++i) {
      int idx = i * 256 + tid;
      int kk = idx >> 5, c = idx & 31;
      int gk = k0 + kk;
      float v = 0.f;
      if (gk < FIN) v = (c < HID) ? w_rel[gk * HID + c] : w_root[gk * HID + (c - HID)];
      wreg[i] = v;
    }
  };

  prefetch(kt_beg);
  for (int kt = kt_beg; kt < kt_end; ++kt) {
    __syncthreads();
#pragma unroll
    for (int i = 0; i < 16; ++i) {
      int idx = i * 256 + tid;
      int r = idx >> 5, c = idx & 31;
      xs[c * BM + (r ^ c)] = xreg[i];
    }
#pragma unroll
    for (int i = 0; i < 4; ++i) {
      int idx = i * 256 + tid;
      int kk = idx >> 5, c = idx & 31;
      ws[kk * 32 + c] = wreg[i];
    }
    __syncthreads();
    if (kt + 1 < kt_end) prefetch(kt + 1);
#pragma unroll
    for (int kk = 0; kk < BK; ++kk) {
      float4 xv = *(const float4*)&xs[kk * BM + ((r0 ^ kk) & ~3)];
      float4 wv = *(const float4*)&ws[kk * 32 + c0];
      float comp[4] = {xv.x, xv.y, xv.z, xv.w};
      const int p = kk & 3;
      float xa[4] = {comp[0 ^ p], comp[1 ^ p], comp[2 ^ p], comp[3 ^ p]};
      float wa[4] = {wv.x, wv.y, wv.z, wv.w};
#pragma unroll
      for (int i = 0; i < 4; ++i)
#pragma unroll
        for (int j = 0; j < 4; ++j)
          acc[i][j] = fmaf(xa[i], wa[j], acc[i][j]);
    }
  }

  float* __restrict__ p_out = pbase + (size_t)slice * seg_elems;
  float* __restrict__ a_out = abase + (size_t)slice * seg_elems;
  if (cg < 4) {
#pragma unroll
    for (int i = 0; i < 4; ++i) {
      int gr = row0 + r0 + i;
      if (gr < n) {
        float4 v = {acc[i][0], acc[i][1], acc[i][2], acc[i][3]};
        *(float4*)&p_out[(size_t)gr * HID + c0] = v;
      }
    }
  } else {
    const int cb = c0 - HID;
    float b0 = 0.f, b1 = 0.f, b2v = 0.f, b3 = 0.f;
    if (slice == 0) { b0 = b_rel[cb]; b1 = b_rel[cb+1]; b2v = b_rel[cb+2]; b3 = b_rel[cb+3]; }
#pragma unroll
    for (int i = 0; i < 4; ++i) {
      int gr = row0 + r0 + i;
      if (gr < n) {
        float4 v = {acc[i][0] + b0, acc[i][1] + b1, acc[i][2] + b2v, acc[i][3] + b3};
        *(float4*)&a_out[(size_t)gr * HID + cb] = v;
      }
    }
  }
}

// KR: sum KS split-K partials into slice 0 (float4 granularity).
__global__ __launch_bounds__(256) void k_reduce(
    float* __restrict__ pbase, float* __restrict__ abase,
    size_t seg_elems, int n4) {
  int i = blockIdx.x * 256 + threadIdx.x;
  if (i >= n4) return;
  size_t s4 = seg_elems / 4;
  float4 a = ((const float4*)pbase)[i];
  float4 c = ((const float4*)abase)[i];
#pragma unroll
  for (int s = 1; s < KS; ++s) {
    float4 b = ((const float4*)pbase)[i + s * s4];
    float4 d = ((const float4*)abase)[i + s * s4];
    a.x += b.x; a.y += b.y; a.z += b.z; a.w += b.w;
    c.x += d.x; c.y += d.y; c.z += d.z; c.w += d.w;
  }
  ((float4*)pbase)[i] = a;
  ((float4*)abase)[i] = c;
}

// K2: scatter-add 16-wide. 16 threads per edge, 1 HW fp32 atomic each.
// unsafeAtomicAdd -> global_atomic_add_f32 (no CAS retry loop).
__global__ __launch_bounds__(256) void k2_scatter16(
    const int* __restrict__ ei, const float* __restrict__ p,
    float* __restrict__ agg, int nE) {
  long long tid = (long long)blockIdx.x * 256 + threadIdx.x;
  if (tid >= (long long)nE * HID) return;
  int e = (int)(tid >> 4), f = (int)(tid & 15);
  int s = ei[e], d = ei[nE + e];
  unsafeAtomicAdd(agg + (size_t)d * HID + f, p[(size_t)s * HID + f]);
}

// K3: ELU + dual 16x7 projection; out2 gets root part + bias.
__global__ __launch_bounds__(256) void k3_l2(
    const float* __restrict__ agg,
    const float* __restrict__ w_root2, const float* __restrict__ w_rel2,
    const float* __restrict__ b2,
    float* __restrict__ p2, float* __restrict__ out2, int n) {
  int i = blockIdx.x * 256 + threadIdx.x;
  if (i >= n) return;
  const float4* a4 = (const float4*)(agg + (size_t)i * HID);
  float h[HID];
#pragma unroll
  for (int q = 0; q < 4; ++q) {
    float4 v = a4[q];
    float t[4] = {v.x, v.y, v.z, v.w};
#pragma unroll
    for (int j = 0; j < 4; ++j)
      h[4*q + j] = t[j] > 0.f ? t[j] : expm1f(t[j]);
  }
#pragma unroll
  for (int c = 0; c < NCLS; ++c) {
    float sr = 0.f, so = b2[c];
#pragma unroll
    for (int k = 0; k < HID; ++k) {
      sr = fmaf(h[k], w_rel2[k * NCLS + c], sr);
      so = fmaf(h[k], w_root2[k * NCLS + c], so);
    }
    p2[(size_t)i * NCLS + c] = sr;
    out2[(size_t)i * NCLS + c] = so;
  }
}

// K4: scatter-add 7-wide. 8 threads/edge, lane 7 idle. HW fp32 atomics.
__global__ __launch_bounds__(256) void k4_scatter7(
    const int* __restrict__ ei, const float* __restrict__ p,
    float* __restrict__ out2, int nE) {
  long long tid = (long long)blockIdx.x * 256 + threadIdx.x;
  int e = (int)(tid >> 3), f = (int)(tid & 7);
  if (e >= nE || f >= NCLS) return;
  int s = ei[e], d = ei[nE + e];
  unsafeAtomicAdd(out2 + (size_t)d * NCLS + f, p[(size_t)s * NCLS + f]);
}

// K5: in-place log_softmax over 7 classes.
__global__ __launch_bounds__(256) void k5_lsm(float* __restrict__ out, int n) {
  int i = blockIdx.x * 256 + threadIdx.x;
  if (i >= n) return;
  float v[NCLS];
  float* o = out + (size_t)i * NCLS;
#pragma unroll
  for (int c = 0; c < NCLS; ++c) v[c] = o[c];
  float m = v[0];
#pragma unroll
  for (int c = 1; c < NCLS; ++c) m = fmaxf(m, v[c]);
  float s = 0.f;
#pragma unroll
  for (int c = 0; c < NCLS; ++c) s += expf(v[c] - m);
  float l = logf(s);
#pragma unroll
  for (int c = 0; c < NCLS; ++c) o[c] = v[c] - m - l;
}

extern "C" void kernel_launch(void* const* d_in, const int* in_sizes, int n_in,
                              void* d_out, int out_size, void* d_ws, size_t ws_size,
                              hipStream_t stream) {
  const float* x       = (const float*)d_in[0];
  const int*   ei      = (const int*)  d_in[1];
  const float* w_root1 = (const float*)d_in[2];
  const float* w_rel1  = (const float*)d_in[3];
  const float* b_rel1  = (const float*)d_in[4];
  const float* w_root2 = (const float*)d_in[5];
  const float* w_rel2  = (const float*)d_in[6];
  const float* b_rel2  = (const float*)d_in[7];
  float* out = (float*)d_out;

  int n  = in_sizes[0] / FIN;   // 100000
  int nE = in_sizes[1] / 2;     // 3200000

  size_t seg = (size_t)n * HID;             // elems per slice buffer
  char* ws = (char*)d_ws;
  float* pbase = (float*)ws;                               // KS * seg f32
  float* abase = pbase + KS * seg;                         // KS * seg f32
  float* p2    = abase + KS * seg;                         // n*7 f32

  int nbN = (n + 255) / 256;

  // layer 1 GEMM (split-K=4)
  dim3 g1((n + BM - 1) / BM, KS);
  k1_gemm<<<g1, 256, 0, stream>>>(x, w_root1, w_rel1, b_rel1,
                                  pbase, abase, seg, n);
  int n4 = n * HID / 4;
  k_reduce<<<(n4 + 255) / 256, 256, 0, stream>>>(pbase, abase, seg, n4);

  // layer 1 aggregation (atomic scatter, 16 lanes/edge)
  long long t2 = (long long)nE * HID;
  k2_scatter16<<<(int)((t2 + 255) / 256), 256, 0, stream>>>(ei, pbase, abase, nE);

  // layer 2
  k3_l2<<<nbN, 256, 0, stream>>>(abase, w_root2, w_rel2, b_rel2, p2, out, n);
  long long t4 = (long long)nE * 8;
  k4_scatter7<<<(int)((t4 + 255) / 256), 256, 0, stream>>>(ei, p2, out, nE);

  k5_lsm<<<nbN, 256, 0, stream>>>(out, n);
}

// Round 7
// 555.896 us; speedup vs baseline: 1.0707x; 1.0707x over previous
//
#include <hip/hip_runtime.h>
#include <hip/hip_bf16.h>
#include <math.h>

#define FIN  1433
#define HID  16
#define NCLS 7
#define BM   128
#define BK   32
#define KS   4
#define KT_TOTAL 45            // ceil(1433/32)
#define KPAD (KT_TOTAL * BK)   // 1440

typedef __attribute__((ext_vector_type(8))) short bf16x8;
typedef __attribute__((ext_vector_type(4))) float f32x4;

// W prep: wT[c][k] bf16 (row stride KPAD), c<16 -> w_rel[k][c], c>=16 -> w_root[k][c-16].
// k >= FIN zero-padded.
__global__ __launch_bounds__(256) void k_wt(
    const float* __restrict__ w_root, const float* __restrict__ w_rel,
    ushort* __restrict__ wT) {
  int idx = blockIdx.x * 256 + threadIdx.x;
  if (idx >= 32 * KPAD) return;
  int c = idx / KPAD, k = idx % KPAD;
  float v = 0.f;
  if (k < FIN) v = (c < HID) ? w_rel[k * HID + c] : w_root[k * HID + (c - HID)];
  __hip_bfloat16 h = __float2bfloat16(v);
  wT[idx] = *(ushort*)&h;
}

// K1: split-K MFMA dual GEMM  C[n x 32] = x @ [w_rel1 | w_root1] in bf16.
// Block 256 thr = 4 waves; wave owns 32 rows; 2x2 16x16x32 MFMA frags per k-tile.
// LDS row-major bf16 tiles (bank-optimal for frag reads); double-buffered.
__global__ __launch_bounds__(256) void k1_mfma(
    const float* __restrict__ x, const ushort* __restrict__ wT,
    const float* __restrict__ b_rel,
    float* __restrict__ pbase, float* __restrict__ abase,
    size_t seg, int n) {
  __shared__ ushort xs[2][BM * BK];   // [row][k], 8 KB each
  __shared__ ushort wsh[2][32 * BK];  // [c][k],   2 KB each

  const int tid  = threadIdx.x;
  const int lane = tid & 63;
  const int wave = tid >> 6;
  const int row0 = blockIdx.x * BM;
  const int slice = blockIdx.y;
  const int kt_beg = (KT_TOTAL * slice) / KS;
  const int kt_end = (KT_TOTAL * (slice + 1)) / KS;

  f32x4 acc[2][2] = {};   // [mf][nf]

  const int sr  = tid >> 5;   // x staging: row = i*8 + sr
  const int sk  = tid & 31;   // x staging: k within tile
  const int wc  = tid >> 3;   // w staging: c (0..31)
  const int wt4 = tid & 7;    // w staging: ushort4 index along k

  float  xr[16];
  ushort4 wr;

  auto load_tile = [&](int kt) {
    const int k0 = kt * BK;
    const int gk = k0 + sk;
    const bool kv = gk < FIN;
#pragma unroll
    for (int i = 0; i < 16; ++i) {
      int gr = row0 + i * 8 + sr;
      xr[i] = (gr < n && kv) ? x[(size_t)gr * FIN + gk] : 0.f;
    }
    wr = *(const ushort4*)&wT[(size_t)wc * KPAD + k0 + wt4 * 4];
  };

  auto store_stage = [&](int b) {
#pragma unroll
    for (int i = 0; i < 16; ++i) {
      __hip_bfloat16 h = __float2bfloat16(xr[i]);
      xs[b][(i * 8 + sr) * BK + sk] = *(ushort*)&h;
    }
    *(ushort4*)&wsh[b][wc * BK + wt4 * 4] = wr;
  };

  const int m = lane & 15, o = lane >> 4;

  auto do_mfma = [&](int b) {
    bf16x8 b0 = *(const bf16x8*)&wsh[b][(m)      * BK + o * 8];
    bf16x8 b1 = *(const bf16x8*)&wsh[b][(16 + m) * BK + o * 8];
#pragma unroll
    for (int mf = 0; mf < 2; ++mf) {
      bf16x8 a = *(const bf16x8*)&xs[b][(wave * 32 + mf * 16 + m) * BK + o * 8];
      acc[mf][0] = __builtin_amdgcn_mfma_f32_16x16x32_bf16(a, b0, acc[mf][0], 0, 0, 0);
      acc[mf][1] = __builtin_amdgcn_mfma_f32_16x16x32_bf16(a, b1, acc[mf][1], 0, 0, 0);
    }
  };

  load_tile(kt_beg);
  store_stage(0);
  __syncthreads();
  for (int t = kt_beg; t < kt_end; ++t) {
    const int b = (t - kt_beg) & 1;
    const bool more = (t + 1) < kt_end;
    if (more) load_tile(t + 1);     // global loads in flight during MFMA
    do_mfma(b);
    if (more) store_stage(b ^ 1);   // other buffer: safe, barrier below publishes
    __syncthreads();
  }

  // epilogue: C/D layout col = lane&15, row = (lane>>4)*4 + j
  float* __restrict__ p_out = pbase + (size_t)slice * seg;
  float* __restrict__ a_out = abase + (size_t)slice * seg;
  const float bv = (slice == 0) ? b_rel[m] : 0.f;
#pragma unroll
  for (int mf = 0; mf < 2; ++mf) {
#pragma unroll
    for (int j = 0; j < 4; ++j) {
      int gr = row0 + wave * 32 + mf * 16 + o * 4 + j;
      if (gr < n) {
        p_out[(size_t)gr * HID + m] = acc[mf][0][j];
        a_out[(size_t)gr * HID + m] = acc[mf][1][j] + bv;
      }
    }
  }
}

// KR: sum KS split-K partials into slice 0 (float4 granularity).
__global__ __launch_bounds__(256) void k_reduce(
    float* __restrict__ pbase, float* __restrict__ abase,
    size_t seg_elems, int n4) {
  int i = blockIdx.x * 256 + threadIdx.x;
  if (i >= n4) return;
  size_t s4 = seg_elems / 4;
  float4 a = ((const float4*)pbase)[i];
  float4 c = ((const float4*)abase)[i];
#pragma unroll
  for (int s = 1; s < KS; ++s) {
    float4 b = ((const float4*)pbase)[i + s * s4];
    float4 d = ((const float4*)abase)[i + s * s4];
    a.x += b.x; a.y += b.y; a.z += b.z; a.w += b.w;
    c.x += d.x; c.y += d.y; c.z += d.z; c.w += d.w;
  }
  ((float4*)pbase)[i] = a;
  ((float4*)abase)[i] = c;
}

// K2: scatter-add 16-wide. 16 threads/edge, 1 HW fp32 atomic each.
__global__ __launch_bounds__(256) void k2_scatter16(
    const int* __restrict__ ei, const float* __restrict__ p,
    float* __restrict__ agg, int nE) {
  long long tid = (long long)blockIdx.x * 256 + threadIdx.x;
  if (tid >= (long long)nE * HID) return;
  int e = (int)(tid >> 4), f = (int)(tid & 15);
  int s = ei[e], d = ei[nE + e];
  unsafeAtomicAdd(agg + (size_t)d * HID + f, p[(size_t)s * HID + f]);
}

// K3: ELU + dual 16x7 projection; out2 gets root part + bias.
__global__ __launch_bounds__(256) void k3_l2(
    const float* __restrict__ agg,
    const float* __restrict__ w_root2, const float* __restrict__ w_rel2,
    const float* __restrict__ b2,
    float* __restrict__ p2, float* __restrict__ out2, int n) {
  int i = blockIdx.x * 256 + threadIdx.x;
  if (i >= n) return;
  const float4* a4 = (const float4*)(agg + (size_t)i * HID);
  float h[HID];
#pragma unroll
  for (int q = 0; q < 4; ++q) {
    float4 v = a4[q];
    float t[4] = {v.x, v.y, v.z, v.w};
#pragma unroll
    for (int j = 0; j < 4; ++j)
      h[4*q + j] = t[j] > 0.f ? t[j] : expm1f(t[j]);
  }
#pragma unroll
  for (int c = 0; c < NCLS; ++c) {
    float sr = 0.f, so = b2[c];
#pragma unroll
    for (int k = 0; k < HID; ++k) {
      sr = fmaf(h[k], w_rel2[k * NCLS + c], sr);
      so = fmaf(h[k], w_root2[k * NCLS + c], so);
    }
    p2[(size_t)i * NCLS + c] = sr;
    out2[(size_t)i * NCLS + c] = so;
  }
}

// K4: scatter-add 7-wide. 8 threads/edge, lane 7 idle.
__global__ __launch_bounds__(256) void k4_scatter7(
    const int* __restrict__ ei, const float* __restrict__ p,
    float* __restrict__ out2, int nE) {
  long long tid = (long long)blockIdx.x * 256 + threadIdx.x;
  int e = (int)(tid >> 3), f = (int)(tid & 7);
  if (e >= nE || f >= NCLS) return;
  int s = ei[e], d = ei[nE + e];
  unsafeAtomicAdd(out2 + (size_t)d * NCLS + f, p[(size_t)s * NCLS + f]);
}

// K5: in-place log_softmax over 7 classes.
__global__ __launch_bounds__(256) void k5_lsm(float* __restrict__ out, int n) {
  int i = blockIdx.x * 256 + threadIdx.x;
  if (i >= n) return;
  float v[NCLS];
  float* o = out + (size_t)i * NCLS;
#pragma unroll
  for (int c = 0; c < NCLS; ++c) v[c] = o[c];
  float m = v[0];
#pragma unroll
  for (int c = 1; c < NCLS; ++c) m = fmaxf(m, v[c]);
  float s = 0.f;
#pragma unroll
  for (int c = 0; c < NCLS; ++c) s += expf(v[c] - m);
  float l = logf(s);
#pragma unroll
  for (int c = 0; c < NCLS; ++c) o[c] = v[c] - m - l;
}

extern "C" void kernel_launch(void* const* d_in, const int* in_sizes, int n_in,
                              void* d_out, int out_size, void* d_ws, size_t ws_size,
                              hipStream_t stream) {
  const float* x       = (const float*)d_in[0];
  const int*   ei      = (const int*)  d_in[1];
  const float* w_root1 = (const float*)d_in[2];
  const float* w_rel1  = (const float*)d_in[3];
  const float* b_rel1  = (const float*)d_in[4];
  const float* w_root2 = (const float*)d_in[5];
  const float* w_rel2  = (const float*)d_in[6];
  const float* b_rel2  = (const float*)d_in[7];
  float* out = (float*)d_out;

  int n  = in_sizes[0] / FIN;   // 100000
  int nE = in_sizes[1] / 2;     // 3200000

  size_t seg = (size_t)n * HID;             // elems per slice buffer
  char* ws = (char*)d_ws;
  float*  pbase = (float*)ws;                              // KS * seg f32
  float*  abase = pbase + KS * seg;                        // KS * seg f32
  float*  p2    = abase + KS * seg;                        // n*7 f32
  ushort* wT    = (ushort*)(p2 + (size_t)n * NCLS);        // 32*1440 bf16

  int nbN = (n + 255) / 256;

  // prep bf16 transposed weights (tiny)
  k_wt<<<(32 * KPAD + 255) / 256, 256, 0, stream>>>(w_root1, w_rel1, wT);

  // layer 1 GEMM (MFMA, split-K=4)
  dim3 g1((n + BM - 1) / BM, KS);
  k1_mfma<<<g1, 256, 0, stream>>>(x, wT, b_rel1, pbase, abase, seg, n);
  int n4 = n * HID / 4;
  k_reduce<<<(n4 + 255) / 256, 256, 0, stream>>>(pbase, abase, seg, n4);

  // layer 1 aggregation (atomic scatter, 16 lanes/edge)
  long long t2 = (long long)nE * HID;
  k2_scatter16<<<(int)((t2 + 255) / 256), 256, 0, stream>>>(ei, pbase, abase, nE);

  // layer 2
  k3_l2<<<nbN, 256, 0, stream>>>(abase, w_root2, w_rel2, b_rel2, p2, out, n);
  long long t4 = (long long)nE * 8;
  k4_scatter7<<<(int)((t4 + 255) / 256), 256, 0, stream>>>(ei, p2, out, nE);

  k5_lsm<<<nbN, 256, 0, stream>>>(out, n);
}

// Round 8
// 479.780 us; speedup vs baseline: 1.2405x; 1.1586x over previous
//
#include <hip/hip_runtime.h>
#include <hip/hip_bf16.h>
#include <math.h>

#define FIN  1433
#define HID  16
#define NCLS 7
#define BM   128
#define BK   32
#define KS   4
#define KT_TOTAL 45            // ceil(1433/32)
#define KPAD (KT_TOTAL * BK)   // 1440

typedef __attribute__((ext_vector_type(8))) short bf16x8;
typedef __attribute__((ext_vector_type(4))) float f32x4;

__device__ inline float bf2f(ushort u) {
  unsigned int t = ((unsigned int)u) << 16;
  return __uint_as_float(t);
}
__device__ inline ushort f2bf(float f) {
  __hip_bfloat16 h = __float2bfloat16(f);
  return *(ushort*)&h;
}
// HW packed bf16 atomic add: mem[addr] (2x bf16) += data (2x bf16).
__device__ inline void pk_atomic_bf16(void* addr, unsigned int data) {
  asm volatile("global_atomic_pk_add_bf16 %0, %1, off"
               :: "v"((unsigned long long)addr), "v"(data) : "memory");
}

// W prep: wT[c][k] bf16 (row stride KPAD); c<16 -> w_rel1, c>=16 -> w_root1.
__global__ __launch_bounds__(256) void k_wt(
    const float* __restrict__ w_root, const float* __restrict__ w_rel,
    ushort* __restrict__ wT) {
  int idx = blockIdx.x * 256 + threadIdx.x;
  if (idx >= 32 * KPAD) return;
  int c = idx / KPAD, k = idx % KPAD;
  float v = 0.f;
  if (k < FIN) v = (c < HID) ? w_rel[k * HID + c] : w_root[k * HID + (c - HID)];
  wT[idx] = f2bf(v);
}

// K1: split-K MFMA dual GEMM; outputs bf16 partials (p = x@w_rel, a = x@w_root [+b]).
__global__ __launch_bounds__(256) void k1_mfma(
    const float* __restrict__ x, const ushort* __restrict__ wT,
    const float* __restrict__ b_rel,
    ushort* __restrict__ pbase, ushort* __restrict__ abase,
    size_t seg, int n) {
  __shared__ ushort xs[2][BM * BK];
  __shared__ ushort wsh[2][32 * BK];

  const int tid  = threadIdx.x;
  const int lane = tid & 63;
  const int wave = tid >> 6;
  const int row0 = blockIdx.x * BM;
  const int slice = blockIdx.y;
  const int kt_beg = (KT_TOTAL * slice) / KS;
  const int kt_end = (KT_TOTAL * (slice + 1)) / KS;

  f32x4 acc[2][2] = {};

  const int sr  = tid >> 5;
  const int sk  = tid & 31;
  const int wc  = tid >> 3;
  const int wt4 = tid & 7;

  float  xr[16];
  ushort4 wr;

  auto load_tile = [&](int kt) {
    const int k0 = kt * BK;
    const int gk = k0 + sk;
    const bool kv = gk < FIN;
#pragma unroll
    for (int i = 0; i < 16; ++i) {
      int gr = row0 + i * 8 + sr;
      xr[i] = (gr < n && kv) ? x[(size_t)gr * FIN + gk] : 0.f;
    }
    wr = *(const ushort4*)&wT[(size_t)wc * KPAD + k0 + wt4 * 4];
  };

  auto store_stage = [&](int b) {
#pragma unroll
    for (int i = 0; i < 16; ++i)
      xs[b][(i * 8 + sr) * BK + sk] = f2bf(xr[i]);
    *(ushort4*)&wsh[b][wc * BK + wt4 * 4] = wr;
  };

  const int m = lane & 15, o = lane >> 4;

  auto do_mfma = [&](int b) {
    bf16x8 b0 = *(const bf16x8*)&wsh[b][(m)      * BK + o * 8];
    bf16x8 b1 = *(const bf16x8*)&wsh[b][(16 + m) * BK + o * 8];
#pragma unroll
    for (int mf = 0; mf < 2; ++mf) {
      bf16x8 a = *(const bf16x8*)&xs[b][(wave * 32 + mf * 16 + m) * BK + o * 8];
      acc[mf][0] = __builtin_amdgcn_mfma_f32_16x16x32_bf16(a, b0, acc[mf][0], 0, 0, 0);
      acc[mf][1] = __builtin_amdgcn_mfma_f32_16x16x32_bf16(a, b1, acc[mf][1], 0, 0, 0);
    }
  };

  load_tile(kt_beg);
  store_stage(0);
  __syncthreads();
  for (int t = kt_beg; t < kt_end; ++t) {
    const int b = (t - kt_beg) & 1;
    const bool more = (t + 1) < kt_end;
    if (more) load_tile(t + 1);
    do_mfma(b);
    if (more) store_stage(b ^ 1);
    __syncthreads();
  }

  ushort* __restrict__ p_out = pbase + (size_t)slice * seg;
  ushort* __restrict__ a_out = abase + (size_t)slice * seg;
  const float bv = (slice == 0) ? b_rel[m] : 0.f;
#pragma unroll
  for (int mf = 0; mf < 2; ++mf) {
#pragma unroll
    for (int j = 0; j < 4; ++j) {
      int gr = row0 + wave * 32 + mf * 16 + o * 4 + j;
      if (gr < n) {
        p_out[(size_t)gr * HID + m] = f2bf(acc[mf][0][j]);
        a_out[(size_t)gr * HID + m] = f2bf(acc[mf][1][j] + bv);
      }
    }
  }
}

// KR: sum KS bf16 partials into slice 0 (uint4 = 8 bf16 per thread).
__global__ __launch_bounds__(256) void k_reduce(
    ushort* __restrict__ pbase, ushort* __restrict__ abase,
    size_t seg, int n8) {
  int i = blockIdx.x * 256 + threadIdx.x;
  if (i >= n8) return;
  float ps[8], as[8];
#pragma unroll
  for (int j = 0; j < 8; ++j) { ps[j] = 0.f; as[j] = 0.f; }
#pragma unroll
  for (int s = 0; s < KS; ++s) {
    uint4 pv = ((const uint4*)(pbase + s * seg))[i];
    uint4 av = ((const uint4*)(abase + s * seg))[i];
    const unsigned int pw[4] = {pv.x, pv.y, pv.z, pv.w};
    const unsigned int aw[4] = {av.x, av.y, av.z, av.w};
#pragma unroll
    for (int q = 0; q < 4; ++q) {
      ps[2*q]   += bf2f((ushort)(pw[q] & 0xffff));
      ps[2*q+1] += bf2f((ushort)(pw[q] >> 16));
      as[2*q]   += bf2f((ushort)(aw[q] & 0xffff));
      as[2*q+1] += bf2f((ushort)(aw[q] >> 16));
    }
  }
  uint4 po, ao;
  unsigned int* pw = (unsigned int*)&po;
  unsigned int* aw = (unsigned int*)&ao;
#pragma unroll
  for (int q = 0; q < 4; ++q) {
    pw[q] = (unsigned int)f2bf(ps[2*q]) | ((unsigned int)f2bf(ps[2*q+1]) << 16);
    aw[q] = (unsigned int)f2bf(as[2*q]) | ((unsigned int)f2bf(as[2*q+1]) << 16);
  }
  ((uint4*)pbase)[i] = po;
  ((uint4*)abase)[i] = ao;
}

// K2: scatter-add 16 bf16 feats, 8 lanes/edge, 1 packed atomic each.
__global__ __launch_bounds__(256) void k2_scatter(
    const int* __restrict__ ei, const ushort* __restrict__ p1,
    ushort* __restrict__ agg, int nE) {
  long long tid = (long long)blockIdx.x * 256 + threadIdx.x;
  if (tid >= (long long)nE * 8) return;
  int e = (int)(tid >> 3), f = (int)(tid & 7);
  int s = ei[e], d = ei[nE + e];
  unsigned int v = ((const unsigned int*)p1)[(size_t)s * 8 + f];
  pk_atomic_bf16((unsigned int*)agg + (size_t)d * 8 + f, v);
}

// K3: ELU + dual 16x7 projection from bf16 agg; p2 bf16[8], out_bf init bf16[8].
__global__ __launch_bounds__(256) void k3_l2(
    const ushort* __restrict__ agg,
    const float* __restrict__ w_root2, const float* __restrict__ w_rel2,
    const float* __restrict__ b2,
    ushort* __restrict__ p2, ushort* __restrict__ out_bf, int n) {
  int i = blockIdx.x * 256 + threadIdx.x;
  if (i >= n) return;
  float h[HID];
  const uint4* arow = (const uint4*)(agg + (size_t)i * HID);
#pragma unroll
  for (int half = 0; half < 2; ++half) {
    uint4 v = arow[half];
    const unsigned int w[4] = {v.x, v.y, v.z, v.w};
#pragma unroll
    for (int q = 0; q < 4; ++q) {
      float t0 = bf2f((ushort)(w[q] & 0xffff));
      float t1 = bf2f((ushort)(w[q] >> 16));
      h[half*8 + 2*q]     = t0 > 0.f ? t0 : expm1f(t0);
      h[half*8 + 2*q + 1] = t1 > 0.f ? t1 : expm1f(t1);
    }
  }
  float sr[8], so[8];
#pragma unroll
  for (int c = 0; c < 8; ++c) { sr[c] = 0.f; so[c] = 0.f; }
#pragma unroll
  for (int c = 0; c < NCLS; ++c) {
    float a = 0.f, b = b2[c];
#pragma unroll
    for (int k = 0; k < HID; ++k) {
      a = fmaf(h[k], w_rel2[k * NCLS + c], a);
      b = fmaf(h[k], w_root2[k * NCLS + c], b);
    }
    sr[c] = a; so[c] = b;
  }
  uint4 pv, ov;
  unsigned int* pw = (unsigned int*)&pv;
  unsigned int* ow = (unsigned int*)&ov;
#pragma unroll
  for (int q = 0; q < 4; ++q) {
    pw[q] = (unsigned int)f2bf(sr[2*q]) | ((unsigned int)f2bf(sr[2*q+1]) << 16);
    ow[q] = (unsigned int)f2bf(so[2*q]) | ((unsigned int)f2bf(so[2*q+1]) << 16);
  }
  ((uint4*)(p2     + (size_t)i * 8))[0] = pv;
  ((uint4*)(out_bf + (size_t)i * 8))[0] = ov;
}

// K4: scatter-add 8 bf16 logits (7 used), 4 lanes/edge, packed atomics.
__global__ __launch_bounds__(256) void k4_scatter(
    const int* __restrict__ ei, const ushort* __restrict__ p2,
    ushort* __restrict__ out_bf, int nE) {
  long long tid = (long long)blockIdx.x * 256 + threadIdx.x;
  if (tid >= (long long)nE * 4) return;
  int e = (int)(tid >> 2), f = (int)(tid & 3);
  int s = ei[e], d = ei[nE + e];
  unsigned int v = ((const unsigned int*)p2)[(size_t)s * 4 + f];
  pk_atomic_bf16((unsigned int*)out_bf + (size_t)d * 4 + f, v);
}

// K5: log_softmax from bf16 logits -> fp32 d_out.
__global__ __launch_bounds__(256) void k5_lsm(
    const ushort* __restrict__ out_bf, float* __restrict__ out, int n) {
  int i = blockIdx.x * 256 + threadIdx.x;
  if (i >= n) return;
  uint4 rv = ((const uint4*)(out_bf + (size_t)i * 8))[0];
  const unsigned int w[4] = {rv.x, rv.y, rv.z, rv.w};
  float v[8];
#pragma unroll
  for (int q = 0; q < 4; ++q) {
    v[2*q]   = bf2f((ushort)(w[q] & 0xffff));
    v[2*q+1] = bf2f((ushort)(w[q] >> 16));
  }
  float m = v[0];
#pragma unroll
  for (int c = 1; c < NCLS; ++c) m = fmaxf(m, v[c]);
  float s = 0.f;
#pragma unroll
  for (int c = 0; c < NCLS; ++c) s += expf(v[c] - m);
  float l = logf(s);
  float* o = out + (size_t)i * NCLS;
#pragma unroll
  for (int c = 0; c < NCLS; ++c) o[c] = v[c] - m - l;
}

extern "C" void kernel_launch(void* const* d_in, const int* in_sizes, int n_in,
                              void* d_out, int out_size, void* d_ws, size_t ws_size,
                              hipStream_t stream) {
  const float* x       = (const float*)d_in[0];
  const int*   ei      = (const int*)  d_in[1];
  const float* w_root1 = (const float*)d_in[2];
  const float* w_rel1  = (const float*)d_in[3];
  const float* b_rel1  = (const float*)d_in[4];
  const float* w_root2 = (const float*)d_in[5];
  const float* w_rel2  = (const float*)d_in[6];
  const float* b_rel2  = (const float*)d_in[7];
  float* out = (float*)d_out;

  int n  = in_sizes[0] / FIN;   // 100000
  int nE = in_sizes[1] / 2;     // 3200000

  size_t seg = (size_t)n * HID;             // bf16 elems per slice buffer
  char* ws = (char*)d_ws;
  ushort* pbase = (ushort*)ws;                             // KS*seg bf16
  ushort* abase = pbase + KS * seg;                        // KS*seg bf16
  ushort* p2    = abase + KS * seg;                        // n*8 bf16
  ushort* outbf = p2 + (size_t)n * 8;                      // n*8 bf16
  ushort* wT    = outbf + (size_t)n * 8;                   // 32*1440 bf16

  int nbN = (n + 255) / 256;

  k_wt<<<(32 * KPAD + 255) / 256, 256, 0, stream>>>(w_root1, w_rel1, wT);

  dim3 g1((n + BM - 1) / BM, KS);
  k1_mfma<<<g1, 256, 0, stream>>>(x, wT, b_rel1, pbase, abase, seg, n);
  int n8 = n * HID / 8;
  k_reduce<<<(n8 + 255) / 256, 256, 0, stream>>>(pbase, abase, seg, n8);

  long long t2 = (long long)nE * 8;
  k2_scatter<<<(int)((t2 + 255) / 256), 256, 0, stream>>>(ei, pbase, abase, nE);

  k3_l2<<<nbN, 256, 0, stream>>>(abase, w_root2, w_rel2, b_rel2, p2, outbf, n);

  long long t4 = (long long)nE * 4;
  k4_scatter<<<(int)((t4 + 255) / 256), 256, 0, stream>>>(ei, p2, outbf, nE);

  k5_lsm<<<nbN, 256, 0, stream>>>(outbf, out, n);
}